// Round 7
// baseline (148.260 us; speedup 1.0000x reference)
//
#include <hip/hip_runtime.h>
#include <hip/hip_bf16.h>

// Linear layer: out[M,N] = x[M,K] @ W[N,K]^T + b[N], fp32 in/out.
// M=32768, N=512, K=512. bf16 MFMA, fp32 accumulate.
// R5-R9: 2-phase 128x128, 4-wave blocks -> 53-56 us, ~2.0 TB/s, latency-
//   bound (MFMA 11%, VALU 9%, occ 20%). R9 falsified vmcnt-drain theory.
// R10: 128x256 1-block/CU "deep-ILP" -> 63 us. Coarse clump, not a real
//   phase interleave (m196 anti-pattern), and lost cross-block TLP.
// R11 (this): combine BOTH levers for the first time:
//   * TLP: 512thr/8 waves, wave=64x32 (acc 32 VGPR), LDS 64 KB
//     -> 2 blocks/CU, 16 waves/CU (needs VGPR<=128: launch_bounds(512,4);
//     budget ~115: acc32 + ld32 + frags24 + addr~25).
//   * Interleave: per K-tile (BK=64) 2 phases x 8 MFMA:
//     {ds_read frags || issue lead-1 loads | bar | setprio MFMA | bar}
//     {ds_read ks1  || cvt+ds_write next   | MFMA | lgkm-only bar}.
//   * XCD-chunked bijective swizzle (1024%8==0): 4 n-blocks of an m-tile
//     share one XCD L2 -> A fetched once from HBM.
//   Gates: VGPR<=128, WRITE~66MB (no spills), conflicts ~0.

#define M_DIM 32768
#define N_DIM 512
#define K_DIM 512
#define BM 128
#define BN 128
#define BK 64          // f32 words per K-tile
#define KT (K_DIM / BK)   // 8

typedef __bf16 bf16x8 __attribute__((ext_vector_type(8)));
typedef __bf16 bf16x4 __attribute__((ext_vector_type(4)));
typedef float floatx4 __attribute__((ext_vector_type(4)));

__global__ __launch_bounds__(512, 4) void linear_ph(
    const float* __restrict__ A,    // [M, K]
    const float* __restrict__ W,    // [N, K]
    const float* __restrict__ bias, // [N]
    float* __restrict__ C)          // [M, N]
{
    // Rows are 64 bf16 = 128 B. T2 swizzle: 16B-chunk c' = c ^ (row&7)
    // (same formulas as R10, correctness-verified there: absmax 0.015625).
    __shared__ __bf16 sA[2][BM * BK];   // 2 x 16 KB
    __shared__ __bf16 sW[2][BN * BK];   // 2 x 16 KB  (total 64 KB)

    const int t = threadIdx.x;
    // Bijective XCD chunking: xcd = bid&7, idx = bid>>3 (1024 % 8 == 0).
    // Within an XCD wgid is contiguous -> all 4 nT of an mT co-located.
    const int wgid = (blockIdx.x & 7) * 128 + (blockIdx.x >> 3);
    const int nT = wgid & 3;
    const int mT = wgid >> 2;
    const int mBlock = mT * BM;
    const int nBlock = nT * BN;

    const int wid = t >> 6;
    const int lane = t & 63;
    const int mW = (wid >> 2) * 64;     // 2 wave-rows of 64
    const int nW = (wid & 3) * 32;      // 4 wave-cols of 32
    const int kh = lane >> 4;
    const int l16 = lane & 15;
    const int sxz = (l16 & 7) << 3;     // frag-read swizzle term (elems)

    floatx4 acc[4][2];
#pragma unroll
    for (int i = 0; i < 4; ++i)
#pragma unroll
        for (int j = 0; j < 2; ++j)
            acc[i][j] = (floatx4)0.f;

    // Staging map: thread covers 16B chunk c of rows rg+32p (p<4) for both
    // A and W tiles (identical 128x64 geometry). 16 thr x 16 B = one 256 B
    // row -> fully coalesced.
    const int c16 = t & 15;
    const int rg = t >> 4;              // 0..31
    const float* aCol = A + (size_t)(mBlock + rg) * K_DIM + c16 * 4;
    const float* wCol = W + (size_t)(nBlock + rg) * K_DIM + c16 * 4;
    // LDS write offsets (elems): r*64 + ((c16*4) ^ ((r&7)<<3)); r&7 == rg&7.
    const int axz = (rg & 7) << 3;
    int wofs[4];
#pragma unroll
    for (int p = 0; p < 4; ++p)
        wofs[p] = (rg + 32 * p) * BK + ((c16 * 4) ^ axz);

    floatx4 ld[8];                       // lead-1 in-flight set (32 VGPR)

#define STAGE_LOAD(kt)                                                        \
    {                                                                         \
        _Pragma("unroll") for (int p = 0; p < 4; ++p) {                       \
            ld[p] = *(const floatx4*)(aCol + (kt)*BK +                        \
                                      (size_t)(32 * p) * K_DIM);              \
            ld[4 + p] = *(const floatx4*)(wCol + (kt)*BK +                    \
                                          (size_t)(32 * p) * K_DIM);          \
        }                                                                     \
    }

#define STAGE_WRITE(bufi)                                                     \
    {                                                                         \
        _Pragma("unroll") for (int p = 0; p < 4; ++p) {                       \
            bf16x4 va, vw;                                                    \
            _Pragma("unroll") for (int j = 0; j < 4; ++j) {                   \
                va[j] = (__bf16)ld[p][j];                                     \
                vw[j] = (__bf16)ld[4 + p][j];                                 \
            }                                                                 \
            *(bf16x4*)&sA[(bufi)][wofs[p]] = va;                              \
            *(bf16x4*)&sW[(bufi)][wofs[p]] = vw;                              \
        }                                                                     \
    }

    // One phase = one 32-wide k-slice: aF[4] + wF[2] (6 ds_read_b128),
    // 8 MFMA. Frag elem addr: row*64 + ((ks*32 + kh*8) ^ ((row&7)<<3));
    // row&7 == l16&7 for all frag rows (mW, nW, i*16 are multiples of 16).
#define FRAGS(curp, ksp)                                                      \
    bf16x8 aF[4], wF[2];                                                      \
    _Pragma("unroll") for (int i = 0; i < 4; ++i)                             \
        aF[i] = *(const bf16x8*)&sA[(curp)][(mW + i * 16 + l16) * BK +        \
                                           (((ksp)*32 + kh * 8) ^ sxz)];      \
    _Pragma("unroll") for (int j = 0; j < 2; ++j)                             \
        wF[j] = *(const bf16x8*)&sW[(curp)][(nW + j * 16 + l16) * BK +        \
                                           (((ksp)*32 + kh * 8) ^ sxz)];

#define MFMA8()                                                               \
    __builtin_amdgcn_s_setprio(1);                                            \
    _Pragma("unroll") for (int mi = 0; mi < 4; ++mi)                          \
        _Pragma("unroll") for (int ni = 0; ni < 2; ++ni)                      \
            acc[mi][ni] = __builtin_amdgcn_mfma_f32_16x16x32_bf16(            \
                aF[mi], wF[ni], acc[mi][ni], 0, 0, 0);                        \
    __builtin_amdgcn_s_setprio(0);

    // Prologue: stage tile 0 into buf 0.
    STAGE_LOAD(0);
    STAGE_WRITE(0);
    asm volatile("s_waitcnt lgkmcnt(0)" ::: "memory");
    __builtin_amdgcn_s_barrier();

    int cur = 0;
    for (int kt = 0; kt < KT; ++kt) {
        // ---- phase 0: frags ks=0 || issue lead-1 loads ----
        {
            FRAGS(cur, 0);
            if (kt + 1 < KT)
                STAGE_LOAD(kt + 1);
            __builtin_amdgcn_sched_barrier(0);  // pin issue before compute
            __builtin_amdgcn_s_barrier();       // align waves (no drain:
                                                // compiler tracks frag deps)
            MFMA8();
            __builtin_amdgcn_s_barrier();
        }
        // ---- phase 1: frags ks=1 || cvt + ds_write next tile ----
        {
            FRAGS(cur, 1);
            if (kt + 1 < KT)
                STAGE_WRITE(cur ^ 1);           // vmcnt waits inserted here
            MFMA8();
            asm volatile("s_waitcnt lgkmcnt(0)" ::: "memory");
            __builtin_amdgcn_s_barrier();       // writes visible; buffer flip
        }
        cur ^= 1;
    }

#undef STAGE_LOAD
#undef STAGE_WRITE
#undef FRAGS
#undef MFMA8

    // Epilogue: D mapping col = lane&15, row = (lane>>4)*4 + reg (verified
    // R5-R10).
#pragma unroll
    for (int ni = 0; ni < 2; ++ni) {
        const int gcol = nBlock + nW + ni * 16 + l16;
        const float bv = bias[gcol];
#pragma unroll
        for (int mi = 0; mi < 4; ++mi) {
            const int rowB = mBlock + mW + mi * 16 + kh * 4;
#pragma unroll
            for (int r = 0; r < 4; ++r)
                C[(size_t)(rowB + r) * N_DIM + gcol] = acc[mi][ni][r] + bv;
        }
    }
}

extern "C" void kernel_launch(void* const* d_in, const int* in_sizes, int n_in,
                              void* d_out, int out_size, void* d_ws, size_t ws_size,
                              hipStream_t stream) {
    const float* x = (const float*)d_in[0];
    const float* w = (const float*)d_in[1];
    const float* b = (const float*)d_in[2];
    float* out = (float*)d_out;

    dim3 grid((M_DIM / BM) * (N_DIM / BN));  // 1024 blocks
    dim3 block(512);
    linear_ph<<<grid, block, 0, stream>>>(x, w, b, out);
}